// Round 12
// baseline (45.709 us; speedup 1.0000x reference)
//
#include <hip/hip_runtime.h>

// Problem constants (from reference setup_inputs)
#define BB 32     // batch
#define UU 1152   // input_units
#define NN 10     // num_units
#define CC 8      // input_channels
#define DD 16     // channels_per_unit
#define EPS 1e-8f
#define INV_LN2 1.44269504088896341f

// inputs : (B, C, U)        float32
// weights: (U, N, C, D)     float32
// out    : (B, N, U, C, D)  float32
//
// R12: occupancy-clean configuration. Quad split (4 lanes per (b,n,u,c)
// group, 4 d-elements per lane) + lean math (folded iter0, base-2 logits,
// folded squash) + uc-fastest block order (clustered write front).
// Live state ~38 VGPR -> natural 8 waves/SIMD (no launch-bounds forcing,
// no unroll, no spill risk). This isolates the occupancy lever that every
// earlier 8-wave attempt confounded (R2/R6/R7 spilled a >=64-float state;
// R5 doubled state via unroll-2; R3 carried 3 unfolded softmax rounds).
//  - blocks: bi = (b*NN+n)*144 + uc  (uc fastest), u = uc*8 + tid>>5
//  - per wave: stores 1 KB contiguous; weight reads 2x512 B contiguous.

typedef float f32x4 __attribute__((ext_vector_type(4)));

__device__ __forceinline__ float rcp_fast(float x) { return __builtin_amdgcn_rcpf(x); }
__device__ __forceinline__ float rsq_fast(float x) { return __builtin_amdgcn_rsqf(x); }

#if __has_builtin(__builtin_amdgcn_exp2f)
__device__ __forceinline__ float exp2_fast(float x) { return __builtin_amdgcn_exp2f(x); }
#else
__device__ __forceinline__ float exp2_fast(float x) { return __expf(x * 0.6931471805599453f); }
#endif

// sum across the 4 lanes of a quad — 2-step DPP butterfly (pure VALU)
__device__ __forceinline__ float quad_sum(float x) {
    float y = __int_as_float(
        __builtin_amdgcn_update_dpp(0, __float_as_int(x), 0xB1, 0xF, 0xF, true)); // [1,0,3,2]
    x += y;
    y = __int_as_float(
        __builtin_amdgcn_update_dpp(0, __float_as_int(x), 0x4E, 0xF, 0xF, true)); // [2,3,0,1]
    return x + y;
}

__device__ __forceinline__ float hsum4(f32x4 a) {
    return (a.x + a.y) + (a.z + a.w);
}

__device__ __forceinline__ f32x4 exp2_v4(f32x4 a) {
    f32x4 r;
    r.x = exp2_fast(a.x); r.y = exp2_fast(a.y);
    r.z = exp2_fast(a.z); r.w = exp2_fast(a.w);
    return r;
}

__global__ __launch_bounds__(256) void caps_route_kernel(
    const float* __restrict__ inputs,
    const float* __restrict__ weights,
    float* __restrict__ out)
{
    int tid = threadIdx.x;
    int bi  = blockIdx.x;           // 46,080 blocks = (32 b * 10 n) * 144 uc
    int uc  = bi % 144;             // u-chunk FASTEST -> clustered write front
    int bn  = bi / 144;
    int n   = bn % NN;
    int b   = bn / NN;

    int sub = tid & 3;              // which 4-element slice of D
    int c   = (tid >> 2) & 7;
    int u   = uc * 8 + (tid >> 5);  // 8 u per block

    float v = inputs[(b * CC + c) * UU + u];

    const float* wp = weights + ((u * NN + n) * CC + c) * DD + sub * 4;
    f32x4 w4 = *reinterpret_cast<const f32x4*>(wp);

    f32x4 p = w4 * v;
    f32x4 q = p * p;

    // ---- iter 0 (folded): softmax uniform; L = scale0*INV_LN2/16 * q ----
    float sq0 = quad_sum(hsum4(q)) * (1.0f / 256.0f);
    float kk = sq0 * rcp_fast(1.0f + sq0) * rsq_fast(sq0 + EPS)
               * (INV_LN2 / 16.0f);
    f32x4 L = kk * q;

    // ---- iter 1 (base-2 logit update via m = e*q) ----
    {
        f32x4 e = exp2_v4(L);
        float S = quad_sum(hsum4(e));
        f32x4 m = e * q;
        float A = quad_sum(hsum4(m * e));
        float Ssq = S * S;
        float k = A * rsq_fast(fmaf(EPS, Ssq, A)) * rcp_fast(Ssq + A)
                  * INV_LN2;
        L += k * m;
    }

    // ---- iter 2 (final; logit update dead) ----
    {
        f32x4 e = exp2_v4(L);
        float S = quad_sum(hsum4(e));
        f32x4 t = e * p;
        float A = quad_sum(hsum4(t * t));
        float Ssq = S * S;
        float ko = A * rsq_fast(fmaf(EPS, Ssq, A)) * rcp_fast(Ssq + A);

        float* op = out + ((b * NN + n) * UU + u) * (CC * DD) + c * DD + sub * 4;
        *reinterpret_cast<f32x4*>(op) = ko * t;
    }
}

extern "C" void kernel_launch(void* const* d_in, const int* in_sizes, int n_in,
                              void* d_out, int out_size, void* d_ws, size_t ws_size,
                              hipStream_t stream) {
    const float* inputs  = (const float*)d_in[0];
    const float* weights = (const float*)d_in[1];
    float* out = (float*)d_out;

    const long long total = (long long)BB * NN * UU * CC * 4;  // 11,796,480 = 46080*256
    const int block = 256;
    const int grid = (int)(total / block);                     // 46,080
    caps_route_kernel<<<grid, block, 0, stream>>>(inputs, weights, out);
}

// Round 13
// 43.288 us; speedup vs baseline: 1.0559x; 1.0559x over previous
//
#include <hip/hip_runtime.h>

// Problem constants (from reference setup_inputs)
#define BB 32     // batch
#define UU 1152   // input_units
#define NN 10     // num_units
#define CC 8      // input_channels
#define DD 16     // channels_per_unit
#define EPS 1e-8f
#define INV_LN2 1.44269504088896341f

// inputs : (B, C, U)        float32
// weights: (U, N, C, D)     float32
// out    : (B, N, U, C, D)  float32
//
// R13 = R10 verbatim (best measured: 42.85 us). Final kernel.
// One (b,n,u,c,sub) slice per thread; n in the grid; u-chunk fastest in
// blockIdx so the resident blocks form linear write streams. 8-wide lane
// split (2 lanes per 16-elem group, one DPP xor-1 step per reduction).
// Math: folded iter0 (softmax uniform -> sq0 from ||p||^2), base-2 logit
// domain (INV_LN2 folded into the agreement constant), folded squash
// k_o = A * rsqrt(A + eps*S^2) * rcp(S^2 + A)  (== scale/S of reference).
//
// Measured plateau evidence (R5-R12): eight structural variants within
// 42.9-50.3 us; pure-store floor ~27 us (harness fills at 6.9 TB/s),
// compute issue ~14 us; observed time matches their sum in every
// organization -> practical write-limited roofline for this op.

typedef float f32x4 __attribute__((ext_vector_type(4)));

__device__ __forceinline__ float rcp_fast(float x) { return __builtin_amdgcn_rcpf(x); }
__device__ __forceinline__ float rsq_fast(float x) { return __builtin_amdgcn_rsqf(x); }

#if __has_builtin(__builtin_amdgcn_exp2f)
__device__ __forceinline__ float exp2_fast(float x) { return __builtin_amdgcn_exp2f(x); }
#else
__device__ __forceinline__ float exp2_fast(float x) { return __expf(x * 0.6931471805599453f); }
#endif

// sum across a lane PAIR (lanes 2k, 2k+1): one DPP xor-1 step
__device__ __forceinline__ float pair_sum(float x) {
    float y = __int_as_float(
        __builtin_amdgcn_update_dpp(0, __float_as_int(x), 0xB1, 0xF, 0xF, true)); // [1,0,3,2]
    return x + y;
}

__device__ __forceinline__ float hsum4(f32x4 a) {
    return (a.x + a.y) + (a.z + a.w);
}

__device__ __forceinline__ f32x4 exp2_v4(f32x4 a) {
    f32x4 r;
    r.x = exp2_fast(a.x); r.y = exp2_fast(a.y);
    r.z = exp2_fast(a.z); r.w = exp2_fast(a.w);
    return r;
}

__global__ __launch_bounds__(256) void caps_route_kernel(
    const float* __restrict__ inputs,
    const float* __restrict__ weights,
    float* __restrict__ out)
{
    int tid = threadIdx.x;
    int bi  = blockIdx.x;           // 23,040 blocks = (32 b * 10 n) * 72 uc
    int uc  = bi % 72;              // u-chunk FASTEST -> clustered write front
    int bn  = bi / 72;
    int n   = bn % NN;
    int b   = bn / NN;

    int sub = tid & 1;              // low/high 8 elements of D
    int c   = (tid >> 1) & 7;
    int u   = uc * 16 + (tid >> 4); // 16 u per block

    float v = inputs[(b * CC + c) * UU + u];

    const float* wp = weights + ((u * NN + n) * CC + c) * DD + sub * 8;
    f32x4 wa = *reinterpret_cast<const f32x4*>(wp);
    f32x4 wb = *reinterpret_cast<const f32x4*>(wp + 4);

    f32x4 pa = wa * v, pb = wb * v;
    f32x4 qa = pa * pa, qb = pb * pb;

    // ---- iter 0 (folded): softmax uniform; L = scale0*INV_LN2/16 * q ----
    float sq0 = pair_sum(hsum4(qa + qb)) * (1.0f / 256.0f);
    float kk = sq0 * rcp_fast(1.0f + sq0) * rsq_fast(sq0 + EPS)
               * (INV_LN2 / 16.0f);
    f32x4 La = kk * qa, Lb = kk * qb;

    // ---- iter 1 (base-2 logit update via m = e*q) ----
    {
        f32x4 ea = exp2_v4(La), eb = exp2_v4(Lb);
        float S = pair_sum(hsum4(ea + eb));
        f32x4 ma = ea * qa, mb = eb * qb;
        float A = pair_sum(hsum4(ma * ea + mb * eb));
        float Ssq = S * S;
        float k = A * rsq_fast(fmaf(EPS, Ssq, A)) * rcp_fast(Ssq + A)
                  * INV_LN2;
        La += k * ma;  Lb += k * mb;
    }

    // ---- iter 2 (final; logit update dead) ----
    {
        f32x4 ea = exp2_v4(La), eb = exp2_v4(Lb);
        float S = pair_sum(hsum4(ea + eb));
        f32x4 ta = ea * pa, tb = eb * pb;
        float A = pair_sum(hsum4(ta * ta + tb * tb));
        float Ssq = S * S;
        float ko = A * rsq_fast(fmaf(EPS, Ssq, A)) * rcp_fast(Ssq + A);

        float* op = out + ((b * NN + n) * UU + u) * (CC * DD) + c * DD + sub * 8;
        *reinterpret_cast<f32x4*>(op)     = ko * ta;
        *reinterpret_cast<f32x4*>(op + 4) = ko * tb;
    }
}

extern "C" void kernel_launch(void* const* d_in, const int* in_sizes, int n_in,
                              void* d_out, int out_size, void* d_ws, size_t ws_size,
                              hipStream_t stream) {
    const float* inputs  = (const float*)d_in[0];
    const float* weights = (const float*)d_in[1];
    float* out = (float*)d_out;

    const long long total = (long long)BB * NN * UU * CC * 2;  // 5,898,240 = 23040*256
    const int block = 256;
    const int grid = (int)(total / block);                     // 23,040
    caps_route_kernel<<<grid, block, 0, stream>>>(inputs, weights, out);
}